// Round 6
// baseline (1242.992 us; speedup 1.0000x reference)
//
#include <hip/hip_runtime.h>
#include <math.h>

// ============================================================
// PointerDecoderSort — MFMA bf16 (single-product) version.
// R12: R11 failure bisect. R11 (swizzle + asm v_cvt_pk_bf16_f32) produced
// NaN. Index-math audit: every FO swizzle verified equivalent to R10 +
// bijective XOR; an operand-order bug in cvt_pk would only permute finite
// values (passes inf threshold) — NaN requires garbage bf16 bits, which
// fits asm-pk2 writing only the low 16 bits of dst (high half undefined).
// Fix: pk2 = composed pack from the proven f2bf RNE bit-math (lo|hi<<16).
// Keeps ALL of R11's conflict swizzle + paired/vectorized stores.
//  (1) XOR swizzle on ALL FO LDS layouts: logical unit-low l stored at
//      phys l ^ (l>>4). Reads: slane = lane ^ (lane>>4) (free).
//      Writes: 1 extra XOR. Kills the 4-8-way epilogue-store conflicts.
//  (2) paired epilogue stores (dword where consecutive j2).
// Geometry unchanged: 512 thr / 8 waves, 80KiB LDS, 2 blocks/CU.
// Predict vs R10 (934us): bank-conflict 5.0e7 -> ~2.5e7, VALUBusy ~32,
// MfmaUtil 23.7 -> ~25, dur -> ~880.
//
// Layout facts (learn_hip m89/m91/m120):
//   A frag: A[m = lane&15][k = (lane>>4)*8 + j]
//   B frag: B[k = (lane>>4)*8 + j][n = lane&15]
//   C/D   : col = lane&15, row = (lane>>4)*4 + reg
// ============================================================

typedef __attribute__((ext_vector_type(8))) short bf16x8;
typedef __attribute__((ext_vector_type(4))) float f32x4;
typedef __attribute__((ext_vector_type(4))) unsigned u32x4;

#define NEG_FILL (-3.0e38f)   // finite stand-in for -inf (inf-inf = nan in harness diff)

// ---- ws layout (units of 8 shorts = 16 B), single bf16 ----
#define U_Q    0        // 2048 units  : Q rank-queries, A-FO [4mt][8kb][64]
#define U_VE   2048     // 4096 units  : ve_w2  B-FO [16nt][4kb][64]
#define U_QKV  6144     // 24576 units : attn_in_w [48nt][8kb][64]
#define U_WO   30720    // 8192 units  : attn_out_w [16nt][8kb][64]
#define U_F1   38912    // 32768 units : ffn_w1 [64nt][8kb][64]
#define U_F2   71680    // 32768 units : ffn_w2 [16nt][32kb][64]
#define U_KW   104448   // 8192 units  : k_w [16nt][8kb][64]
#define U_TOT  112640   // *16B = 1,802,240 B in d_ws

// ---- LDS layout (shorts) ----
#define SH_H  0         // h residual, A-FO [4mt][8kb][64][8] = 16384 shorts (swizzled)
#define SH_A  16384     // phase-shared region, 16384 shorts (all FO swizzled):
//   ve phase : rbuf-FO [4mt][4kb][64][8] = 8192      at SH_A
//   ffn phase: f1-FO   [4mi][8kb][64][8] = 16384     at SH_A
//   attention: qF(e) SH_A + e*2048        [4mi][64][8]
//              kF(e) SH_A + 4096 + e*2048 [4nt][64][8]
//              vF(e) SH_A + 8192 + e*2048 [2nt][2kb][64][8]
//              aoF(e) SH_A + 12288 + e*2048 [4mi][64][8]
#define SH_SHORTS 32768
// FB region (after shorts): 4096 floats = 8192 shorts.
//   attention: P(e) bf16 A-FO at short-offset SH_SHORTS + e*4096 (swizzled)
//   decode   : SB logits f32 [64][64] XOR-swizzled (P dead by then)
#define FB_FLOATS 4096
#define LDS_BYTES (SH_SHORTS*2 + FB_FLOATS*4)   // 81920 = 80 KiB exactly

__device__ __forceinline__ unsigned short f2bf(float f){
  unsigned u = __float_as_uint(f);
  return (unsigned short)((u + 0x7FFFu + ((u>>16)&1u)) >> 16);
}
__device__ __forceinline__ float bf2f(unsigned short h){
  return __uint_as_float(((unsigned)h) << 16);
}
// packed f32x2 -> bf16x2 (low = a, high = b), composed from proven RNE
// bit-math (R11's asm v_cvt_pk_bf16_f32 produced NaN — high dst half
// suspected undefined on gfx950; do NOT hand-write that instruction).
__device__ __forceinline__ unsigned pk2(float a, float b){
  return (unsigned)f2bf(a) | ((unsigned)f2bf(b) << 16);
}

#define MFMA(a,b,c) __builtin_amdgcn_mfma_f32_16x16x32_bf16((a),(b),(c),0,0,0)
#define SM_SCALE 0.17677669529663687f

// ------------------------------------------------------------
__global__ void __launch_bounds__(256) prep_q(const float* __restrict__ rank_emb,
                                              const float* __restrict__ q_w,
                                              const float* __restrict__ q_b,
                                              short* __restrict__ wsp) {
    int t = blockIdx.x;
    int c = threadIdx.x;
    float acc = q_b[c];
    for (int d = 0; d < 256; d += 4) {
        acc += rank_emb[t*256 + d + 0] * q_w[(d+0)*256 + c]
             + rank_emb[t*256 + d + 1] * q_w[(d+1)*256 + c]
             + rank_emb[t*256 + d + 2] * q_w[(d+2)*256 + c]
             + rank_emb[t*256 + d + 3] * q_w[(d+3)*256 + c];
    }
    int kb = c >> 5, lane = ((c>>3)&3)*16 + (t&15), j = c & 7;
    int u = ((t>>4)*8 + kb)*64 + lane;
    wsp[(U_Q + u)*8 + j] = (short)f2bf(acc);
}

// ------------------------------------------------------------
__global__ void __launch_bounds__(256) prep_w(const float* __restrict__ ve_w2,
                                              const float* __restrict__ attn_in_w,
                                              const float* __restrict__ attn_out_w,
                                              const float* __restrict__ ffn_w1,
                                              const float* __restrict__ ffn_w2,
                                              const float* __restrict__ k_w,
                                              short* __restrict__ wsp) {
    int r = blockIdx.x*256 + threadIdx.x;
    const float* w; int N, K, base;
    if (r < 4096)                { w = ve_w2;      N = 256;  K = 128;  base = U_VE;  }
    else if ((r -= 4096)  < 24576) { w = attn_in_w;  N = 768;  K = 256;  base = U_QKV; }
    else if ((r -= 24576) < 8192)  { w = attn_out_w; N = 256;  K = 256;  base = U_WO;  }
    else if ((r -= 8192)  < 32768) { w = ffn_w1;     N = 1024; K = 256;  base = U_F1;  }
    else if ((r -= 32768) < 32768) { w = ffn_w2;     N = 256;  K = 1024; base = U_F2;  }
    else     { r -= 32768;           w = k_w;        N = 256;  K = 256;  base = U_KW;  }
    int KB = K >> 5;
    int lane = r & 63;
    int kb   = (r >> 6) % KB;
    int nt   = r / (64 * KB);
    int n  = nt*16 + (lane & 15);
    int k0 = kb*32 + (lane >> 4)*8;
    bf16x8 hv;
#pragma unroll
    for (int j = 0; j < 8; j++) hv[j] = (short)f2bf(w[(size_t)(k0 + j)*N + n]);
    *(bf16x8*)&wsp[(size_t)(base + r) * 8] = hv;
}

// ------------------------------------------------------------
// fused per-batch-element kernel: 512 threads = 8 waves
// ------------------------------------------------------------
__global__ void __launch_bounds__(512, 4) fused_kernel(
    const float* __restrict__ x,
    const float* __restrict__ ve_w1, const float* __restrict__ ve_b1,
    const float* __restrict__ ve_b2,
    const float* __restrict__ pos_emb,
    const float* __restrict__ attn_in_b,
    const float* __restrict__ attn_out_b,
    const float* __restrict__ ffn_b1, const float* __restrict__ ffn_b2,
    const float* __restrict__ ln1_g, const float* __restrict__ ln1_b,
    const float* __restrict__ ln2_g, const float* __restrict__ ln2_b,
    const float* __restrict__ k_b,
    const short* __restrict__ wsp,
    float* __restrict__ out)
{
    extern __shared__ short sm[];
    float* smf  = (float*)(sm + SH_SHORTS);
    float* SB   = smf;             // decode logits [64][64], XOR-swizzled (post-attn)

    const int tid  = threadIdx.x;
    const int b    = blockIdx.x;
    const int w    = tid >> 6;     // 0..7
    const int lane = tid & 63;
    const int quad = lane >> 4;
    const int lcol = lane & 15;
    const int slane = lane ^ (lane >> 4);   // physical slot of logical lane (FO swizzle)

    const bf16x8* wsv = (const bf16x8*)wsp;
    const bf16x8* HFu = (const bf16x8*)&sm[SH_H];

    // ---------- phase 1a: rbuf = relu(x*w1+b1) -> FO (swizzled) ----------
#pragma unroll
    for (int i = 0; i < 2; i++) {
        int u = tid + i*512;       // 1024 units on 512 threads
        int l3 = u & 63, kb = (u >> 6) & 3, mt = u >> 8;
        int m  = mt*16 + (l3 & 15);
        int k0 = kb*32 + (l3 >> 4)*8;
        float xv = x[b*64 + m];    // L1-served broadcast
        float f[8];
#pragma unroll
        for (int j = 0; j < 8; j++) {
            float t0 = xv * ve_w1[k0 + j] + ve_b1[k0 + j];
            f[j] = t0 > 0.f ? t0 : 0.f;
        }
        u32x4 hv;
        hv[0] = pk2(f[0], f[1]); hv[1] = pk2(f[2], f[3]);
        hv[2] = pk2(f[4], f[5]); hv[3] = pk2(f[6], f[7]);
        int sl3 = l3 ^ (l3 >> 4);
        *(u32x4*)&sm[SH_A + ((u & ~63) | sl3)*8] = hv;
    }
    __syncthreads();

    // ---------- phase 1b: h = rbuf @ ve_w2 + b2 + pos (M64 K128 N256) ----------
    {
        f32x4 acc[2][4];
#pragma unroll
        for (int s = 0; s < 2; s++)
#pragma unroll
            for (int mi = 0; mi < 4; mi++) acc[s][mi] = (f32x4){0.f,0.f,0.f,0.f};
#pragma unroll
        for (int kb = 0; kb < 4; kb++) {
            bf16x8 bh0 = wsv[U_VE + ((w    )*4+kb)*64 + lane];
            bf16x8 bh1 = wsv[U_VE + ((w + 8)*4+kb)*64 + lane];
#pragma unroll
            for (int mi = 0; mi < 4; mi++) {
                bf16x8 ah = *(const bf16x8*)&sm[SH_A + ((mi*4+kb)*64 + slane)*8];
                acc[0][mi] = MFMA(ah, bh0, acc[0][mi]);
                acc[1][mi] = MFMA(ah, bh1, acc[1][mi]);
            }
        }
        __syncthreads();   // rbuf reads complete (SH_A reused later)
#pragma unroll
        for (int s = 0; s < 2; s++) {
            int n = (w + s*8)*16 + lcol;
            int hi = (n>>3)&3, kb2 = n>>5, j2 = n&7;
#pragma unroll
            for (int mi = 0; mi < 4; mi++) {
                float vv[4];
#pragma unroll
                for (int reg = 0; reg < 4; reg++) {
                    int m = mi*16 + quad*4 + reg;
                    vv[reg] = acc[s][mi][reg] + ve_b2[n] + pos_emb[m*256 + n];
                }
#pragma unroll
                for (int rp = 0; rp < 2; rp++) {
                    unsigned r = pk2(vv[2*rp], vv[2*rp+1]);
                    int m0 = quad*4 + 2*rp;
                    int gbase = (mi*8 + kb2)*64 + hi*16;
                    sm[SH_H + (gbase + ((m0  )^hi))*8 + j2] = (short)r;
                    sm[SH_H + (gbase + ((m0+1)^hi))*8 + j2] = (short)(r >> 16);
                }
            }
        }
    }
    __syncthreads();

    // ---------- attention ----------
    f32x4 aoacc[2][4];             // attn-out accum: ntiles w, w+8
#pragma unroll
    for (int s = 0; s < 2; s++)
#pragma unroll
        for (int mi = 0; mi < 4; mi++) aoacc[s][mi] = (f32x4){0.f,0.f,0.f,0.f};

    const int il = w & 3;
    const int eo = il >> 1, ch = il & 1;   // qkv epilogue head / col-half

    // qkv for head pair p (rebalanced): w<4: q(full) + v(mi0,1); w>=4: k(full) + v(mi2,3)
    auto qkv_phase = [&](int p) {
        int ntv = 32 + 4*p + il;
        int cc = ch*16 + lcol;
        int hic = (cc>>3)&3, j2c = cc&7;
        if (w < 4) {
            int ntg = 4*p + il;
            f32x4 acc[4];
#pragma unroll
            for (int mi = 0; mi < 4; mi++) acc[mi] = (f32x4){0.f,0.f,0.f,0.f};
#pragma unroll
            for (int kb = 0; kb < 8; kb++) {
                bf16x8 bh = wsv[U_QKV + (ntg*8+kb)*64 + lane];
#pragma unroll
                for (int mi = 0; mi < 4; mi++)
                    acc[mi] = MFMA(HFu[(mi*8+kb)*64 + slane], bh, acc[mi]);
            }
            float bq = attn_in_b[ntg*16 + lcol];
#pragma unroll
            for (int mi = 0; mi < 4; mi++)
#pragma unroll
                for (int rp = 0; rp < 2; rp++) {
                    unsigned r = pk2(acc[mi][2*rp] + bq, acc[mi][2*rp+1] + bq);
                    int m0 = quad*4 + 2*rp;
                    int gbase = SH_A + eo*2048 + (mi*64 + hic*16)*8;
                    sm[gbase + (((m0  )^hic))*8 + j2c] = (short)r;       // q: A-FO
                    sm[gbase + (((m0+1)^hic))*8 + j2c] = (short)(r >> 16);
                }
            // v half: mi 0..1
            f32x4 va[2];
            va[0] = (f32x4){0.f,0.f,0.f,0.f}; va[1] = (f32x4){0.f,0.f,0.f,0.f};
#pragma unroll
            for (int kb = 0; kb < 8; kb++) {
                bf16x8 bh = wsv[U_QKV + (ntv*8+kb)*64 + lane];
                va[0] = MFMA(HFu[(0*8+kb)*64 + slane], bh, va[0]);
                va[1] = MFMA(HFu[(1*8+kb)*64 + slane], bh, va[1]);
            }
            float bv = attn_in_b[ntv*16 + lcol];
#pragma unroll
            for (int mi = 0; mi < 2; mi++)
#pragma unroll
                for (int rp = 0; rp < 2; rp++) {
                    unsigned r = pk2(va[mi][2*rp] + bv, va[mi][2*rp+1] + bv);
                    int m0 = mi*16 + quad*4 + 2*rp;
                    int kb2 = m0>>5, hi2 = (m0>>3)&3;         // v: B-FO (k=seq, n=cc)
                    int X = SH_A + 8192 + eo*2048
                          + (((ch*2 + kb2)*64 + hi2*16 + (lcol^hi2)))*8 + (m0&7);
                    *(unsigned*)&sm[X] = r;                   // 2 consecutive j2
                }
        } else {
            int ntg = 16 + 4*p + il;
            f32x4 acc[4];
#pragma unroll
            for (int mi = 0; mi < 4; mi++) acc[mi] = (f32x4){0.f,0.f,0.f,0.f};
#pragma unroll
            for (int kb = 0; kb < 8; kb++) {
                bf16x8 bh = wsv[U_QKV + (ntg*8+kb)*64 + lane];
#pragma unroll
                for (int mi = 0; mi < 4; mi++)
                    acc[mi] = MFMA(HFu[(mi*8+kb)*64 + slane], bh, acc[mi]);
            }
            float bk = attn_in_b[ntg*16 + lcol];
#pragma unroll
            for (int mi = 0; mi < 4; mi++)
#pragma unroll
                for (int rp = 0; rp < 2; rp++) {
                    unsigned r = pk2(acc[mi][2*rp] + bk, acc[mi][2*rp+1] + bk);
                    int m0 = quad*4 + 2*rp;
                    int gbase = SH_A + 4096 + eo*2048 + (mi*64 + hic*16)*8;
                    sm[gbase + (((m0  )^hic))*8 + j2c] = (short)r;       // k: B-FO
                    sm[gbase + (((m0+1)^hic))*8 + j2c] = (short)(r >> 16);
                }
            // v half: mi 2..3
            f32x4 va[2];
            va[0] = (f32x4){0.f,0.f,0.f,0.f}; va[1] = (f32x4){0.f,0.f,0.f,0.f};
#pragma unroll
            for (int kb = 0; kb < 8; kb++) {
                bf16x8 bh = wsv[U_QKV + (ntv*8+kb)*64 + lane];
                va[0] = MFMA(HFu[(2*8+kb)*64 + slane], bh, va[0]);
                va[1] = MFMA(HFu[(3*8+kb)*64 + slane], bh, va[1]);
            }
            float bv = attn_in_b[ntv*16 + lcol];
#pragma unroll
            for (int mi2 = 0; mi2 < 2; mi2++)
#pragma unroll
                for (int rp = 0; rp < 2; rp++) {
                    unsigned r = pk2(va[mi2][2*rp] + bv, va[mi2][2*rp+1] + bv);
                    int m0 = (mi2+2)*16 + quad*4 + 2*rp;
                    int kb2 = m0>>5, hi2 = (m0>>3)&3;
                    int X = SH_A + 8192 + eo*2048
                          + (((ch*2 + kb2)*64 + hi2*16 + (lcol^hi2)))*8 + (m0&7);
                    *(unsigned*)&sm[X] = r;
                }
        }
    };

    // scores + in-register softmax + direct bf16 A-FO P write (waves 0..3)
    auto scores_sm = [&](int e) {
        if (w < 4) {
            int mi = w;
            bf16x8 ah = *(const bf16x8*)&sm[SH_A + e*2048 + (mi*64 + slane)*8];
            f32x4 sa[4];
#pragma unroll
            for (int ni = 0; ni < 4; ni++) {
                bf16x8 bh = *(const bf16x8*)&sm[SH_A + 4096 + e*2048 + (ni*64 + slane)*8];
                f32x4 z = (f32x4){0.f,0.f,0.f,0.f};
                sa[ni] = MFMA(ah, bh, z);
            }
            int lo3 = lcol>>3, j2 = lcol&7;
            int hiA = lo3, hiB = 2 + lo3;
            int pbase = SH_SHORTS + e*4096;
#pragma unroll
            for (int reg = 0; reg < 4; reg++) {
                float v0 = sa[0][reg]*SM_SCALE, v1 = sa[1][reg]*SM_SCALE;
                float v2 = sa[2][reg]*SM_SCALE, v3 = sa[3][reg]*SM_SCALE;
                float mx = fmaxf(fmaxf(v0,v1), fmaxf(v2,v3));
#pragma unroll
                for (int off = 8; off >= 1; off >>= 1) mx = fmaxf(mx, __shfl_xor(mx, off, 64));
                v0 = __expf(v0-mx); v1 = __expf(v1-mx); v2 = __expf(v2-mx); v3 = __expf(v3-mx);
                float s = v0+v1+v2+v3;
#pragma unroll
                for (int off = 8; off >= 1; off >>= 1) s += __shfl_xor(s, off, 64);
                float inv = 1.0f / s;
                int mr = quad*4 + reg;                 // m & 15
                unsigned r01 = pk2(v0*inv, v1*inv);    // ni 0 (hiA), ni 1 (hiB)
                unsigned r23 = pk2(v2*inv, v3*inv);    // ni 2 (hiA), ni 3 (hiB)
                sm[pbase + ((mi*2+0)*64 + hiA*16 + (mr^hiA))*8 + j2] = (short)r01;
                sm[pbase + ((mi*2+0)*64 + hiB*16 + (mr^hiB))*8 + j2] = (short)(r01 >> 16);
                sm[pbase + ((mi*2+1)*64 + hiA*16 + (mr^hiA))*8 + j2] = (short)r23;
                sm[pbase + ((mi*2+1)*64 + hiB*16 + (mr^hiB))*8 + j2] = (short)(r23 >> 16);
            }
        }
    };

    // PV: 8 tiles on 8 waves -> aoF(e); P read from FB region
    auto pv_phase = [&](int e) {
        int mi = w & 3, ni = w >> 2;
        f32x4 pv = (f32x4){0.f,0.f,0.f,0.f};
#pragma unroll
        for (int kb = 0; kb < 2; kb++) {
            bf16x8 ah = *(const bf16x8*)&sm[SH_SHORTS + e*4096 + ((mi*2+kb)*64 + slane)*8];
            bf16x8 bh = *(const bf16x8*)&sm[SH_A + 8192 + e*2048 + ((ni*2+kb)*64 + slane)*8];
            pv = MFMA(ah, bh, pv);
        }
        int hi = (ni*2 + (lcol>>3))&3, j2 = lcol&7;
#pragma unroll
        for (int rp = 0; rp < 2; rp++) {
            unsigned r = pk2(pv[2*rp], pv[2*rp+1]);
            int m0 = quad*4 + 2*rp;
            int gbase = SH_A + 12288 + e*2048 + (mi*64 + hi*16)*8;
            sm[gbase + (((m0  )^hi))*8 + j2] = (short)r;
            sm[gbase + (((m0+1)^hi))*8 + j2] = (short)(r >> 16);
        }
    };

    // attn_out partial: ntiles w, w+8; K-chunk = head hh
    auto wo_phase = [&](int hh, int e) {
        bf16x8 bh0 = wsv[U_WO + ((w    )*8 + hh)*64 + lane];
        bf16x8 bh1 = wsv[U_WO + ((w + 8)*8 + hh)*64 + lane];
#pragma unroll
        for (int mi = 0; mi < 4; mi++) {
            bf16x8 ah = *(const bf16x8*)&sm[SH_A + 12288 + e*2048 + (mi*64 + slane)*8];
            aoacc[0][mi] = MFMA(ah, bh0, aoacc[0][mi]);
            aoacc[1][mi] = MFMA(ah, bh1, aoacc[1][mi]);
        }
    };

    qkv_phase(0);
    __syncthreads();
    for (int p = 0; p < 4; p++) {
        scores_sm(0);                       // F1
        __syncthreads();
        pv_phase(0);  scores_sm(1);         // F2
        __syncthreads();
        wo_phase(2*p, 0);  pv_phase(1);     // F3
        __syncthreads();
        wo_phase(2*p+1, 1);                 // F4
        if (p < 3) qkv_phase(p+1);
        __syncthreads();
    }

    // ---------- residual += attn_out + bias ----------
#pragma unroll
    for (int s = 0; s < 2; s++) {
        int n = (w + s*8)*16 + lcol;
        int hi = (n>>3)&3, kb2 = n>>5, j2 = n&7;
        float bo = attn_out_b[n];
#pragma unroll
        for (int mi = 0; mi < 4; mi++) {
            float vv[4];
#pragma unroll
            for (int reg = 0; reg < 4; reg++) {
                int m0 = quad*4 + reg;
                int idx = SH_H + ((mi*8 + kb2)*64 + hi*16 + (m0^hi))*8 + j2;
                vv[reg] = bf2f((unsigned short)sm[idx]) + aoacc[s][mi][reg] + bo;
            }
#pragma unroll
            for (int rp = 0; rp < 2; rp++) {
                unsigned r = pk2(vv[2*rp], vv[2*rp+1]);
                int m0 = quad*4 + 2*rp;
                int gbase = (mi*8 + kb2)*64 + hi*16;
                sm[SH_H + (gbase + ((m0  )^hi))*8 + j2] = (short)r;
                sm[SH_H + (gbase + ((m0+1)^hi))*8 + j2] = (short)(r >> 16);
            }
        }
    }
    __syncthreads();

    // ---------- LayerNorm on h-FO: 8 lanes/row, 32 values each ----------
    auto layernormFO = [&](const float* __restrict__ g, const float* __restrict__ bt) {
        int m = tid >> 3, kb = tid & 7;
        int gb = ((m>>4)*8 + kb)*64;
        int low = m & 15;
        bf16x8 h0 = HFu[gb + 0*16 + (low^0)];
        bf16x8 h1 = HFu[gb + 1*16 + (low^1)];
        bf16x8 h2 = HFu[gb + 2*16 + (low^2)];
        bf16x8 h3 = HFu[gb + 3*16 + (low^3)];
        float v[32];
#pragma unroll
        for (int j = 0; j < 8; j++) {
            v[j]    = bf2f((unsigned short)h0[j]);
            v[8+j]  = bf2f((unsigned short)h1[j]);
            v[16+j] = bf2f((unsigned short)h2[j]);
            v[24+j] = bf2f((unsigned short)h3[j]);
        }
        float sum = 0.f;
#pragma unroll
        for (int i = 0; i < 32; i++) sum += v[i];
#pragma unroll
        for (int off = 4; off >= 1; off >>= 1) sum += __shfl_xor(sum, off, 64);
        float mean = sum * (1.0f/256.0f);
        float s2 = 0.f;
#pragma unroll
        for (int i = 0; i < 32; i++) { float d = v[i] - mean; s2 += d*d; }
#pragma unroll
        for (int off = 4; off >= 1; off >>= 1) s2 += __shfl_xor(s2, off, 64);
        float r = 1.0f / sqrtf(s2 * (1.0f/256.0f) + 1e-5f);
#pragma unroll
        for (int q = 0; q < 4; q++) {
            float o[8];
#pragma unroll
            for (int j = 0; j < 8; j++) {
                int k = kb*32 + q*8 + j;
                o[j] = (v[q*8+j] - mean) * r * g[k] + bt[k];
            }
            u32x4 po;
            po[0] = pk2(o[0], o[1]); po[1] = pk2(o[2], o[3]);
            po[2] = pk2(o[4], o[5]); po[3] = pk2(o[6], o[7]);
            *(u32x4*)&sm[SH_H + (gb + q*16 + (low^q))*8] = po;
        }
        __syncthreads();
    };
    layernormFO(ln1_g, ln1_b);

    // ---------- FFN: 4 chunks of 256 cols (sequential ffn1 streams) ----------
    f32x4 f2acc[2][4];
#pragma unroll
    for (int s = 0; s < 2; s++)
#pragma unroll
        for (int mi = 0; mi < 4; mi++) f2acc[s][mi] = (f32x4){0.f,0.f,0.f,0.f};

    for (int c = 0; c < 4; c++) {
        // ---- ffn1 stream 0: ntile c*16+w ----
        f32x4 a1[4];
#pragma unroll
        for (int mi = 0; mi < 4; mi++) a1[mi] = (f32x4){0.f,0.f,0.f,0.f};
#pragma unroll
        for (int kb = 0; kb < 8; kb++) {
            bf16x8 bh = wsv[U_F1 + ((c*16 + w)*8 + kb)*64 + lane];
#pragma unroll
            for (int mi = 0; mi < 4; mi++) {
                bf16x8 ah = HFu[(mi*8+kb)*64 + slane];
                a1[mi] = MFMA(ah, bh, a1[mi]);
            }
        }
        __syncthreads();   // prev chunk's ffn2 reads of f1 are done
        {
            int n = (c*16 + w)*16 + lcol;
            int kk = w*16 + lcol;
            int hi = (kk>>3)&3, kb2 = kk>>5, j2 = kk&7;
            float bf1 = ffn_b1[n];
#pragma unroll
            for (int mi = 0; mi < 4; mi++)
#pragma unroll
                for (int rp = 0; rp < 2; rp++) {
                    float x0 = a1[mi][2*rp]   + bf1; x0 = x0 > 0.f ? x0 : 0.f;
                    float x1 = a1[mi][2*rp+1] + bf1; x1 = x1 > 0.f ? x1 : 0.f;
                    unsigned r = pk2(x0, x1);
                    int m0 = quad*4 + 2*rp;
                    int gbase = (mi*8 + kb2)*64 + hi*16;
                    sm[SH_A + (gbase + ((m0  )^hi))*8 + j2] = (short)r;
                    sm[SH_A + (gbase + ((m0+1)^hi))*8 + j2] = (short)(r >> 16);
                }
        }
        // ---- ffn1 stream 1: ntile c*16+w+8 ----
#pragma unroll
        for (int mi = 0; mi < 4; mi++) a1[mi] = (f32x4){0.f,0.f,0.f,0.f};
#pragma unroll
        for (int kb = 0; kb < 8; kb++) {
            bf16x8 bh = wsv[U_F1 + ((c*16 + w + 8)*8 + kb)*64 + lane];
#pragma unroll
            for (int mi = 0; mi < 4; mi++) {
                bf16x8 ah = HFu[(mi*8+kb)*64 + slane];
                a1[mi] = MFMA(ah, bh, a1[mi]);
            }
        }
        {
            int n = (c*16 + w + 8)*16 + lcol;
            int kk = (w + 8)*16 + lcol;
            int hi = (kk>>3)&3, kb2 = kk>>5, j2 = kk&7;
            float bf1 = ffn_b1[n];
#pragma unroll
            for (int mi = 0; mi < 4; mi++)
#pragma unroll
                for (int rp = 0; rp < 2; rp++) {
                    float x0 = a1[mi][2*rp]   + bf1; x0 = x0 > 0.f ? x0 : 0.f;
                    float x1 = a1[mi][2*rp+1] + bf1; x1 = x1 > 0.f ? x1 : 0.f;
                    unsigned r = pk2(x0, x1);
                    int m0 = quad*4 + 2*rp;
                    int gbase = (mi*8 + kb2)*64 + hi*16;
                    sm[SH_A + (gbase + ((m0  )^hi))*8 + j2] = (short)r;
                    sm[SH_A + (gbase + ((m0+1)^hi))*8 + j2] = (short)(r >> 16);
                }
        }
        __syncthreads();
        // ---- ffn2 partial: ntiles w, w+8; K-chunk c (256 wide) ----
#pragma unroll 2
        for (int kbl = 0; kbl < 8; kbl++) {
            bf16x8 bh0 = wsv[U_F2 + ((w    )*32 + c*8 + kbl)*64 + lane];
            bf16x8 bh1 = wsv[U_F2 + ((w + 8)*32 + c*8 + kbl)*64 + lane];
#pragma unroll
            for (int mi = 0; mi < 4; mi++) {
                bf16x8 ah = *(const bf16x8*)&sm[SH_A + ((mi*8+kbl)*64 + slane)*8];
                f2acc[0][mi] = MFMA(ah, bh0, f2acc[0][mi]);
                f2acc[1][mi] = MFMA(ah, bh1, f2acc[1][mi]);
            }
        }
        // barrier at top of next iteration protects f1 overwrite
    }
    __syncthreads();
    // residual += ffn2 + bias
#pragma unroll
    for (int s = 0; s < 2; s++) {
        int n = (w + s*8)*16 + lcol;
        int hi = (n>>3)&3, kb2 = n>>5, j2 = n&7;
        float bo = ffn_b2[n];
#pragma unroll
        for (int mi = 0; mi < 4; mi++) {
            float vv[4];
#pragma unroll
            for (int reg = 0; reg < 4; reg++) {
                int m0 = quad*4 + reg;
                int idx = SH_H + ((mi*8 + kb2)*64 + hi*16 + (m0^hi))*8 + j2;
                vv[reg] = bf2f((unsigned short)sm[idx]) + f2acc[s][mi][reg] + bo;
            }
#pragma unroll
            for (int rp = 0; rp < 2; rp++) {
                unsigned r = pk2(vv[2*rp], vv[2*rp+1]);
                int m0 = quad*4 + 2*rp;
                int gbase = (mi*8 + kb2)*64 + hi*16;
                sm[SH_H + (gbase + ((m0  )^hi))*8 + j2] = (short)r;
                sm[SH_H + (gbase + ((m0+1)^hi))*8 + j2] = (short)(r >> 16);
            }
        }
    }
    __syncthreads();
    layernormFO(ln2_g, ln2_b);

    // ---------- kproj: K = enc @ k_w + k_b -> overwrite h-FO as B-FO ----------
    {
        f32x4 kacc[2][4];
#pragma unroll
        for (int s = 0; s < 2; s++)
#pragma unroll
            for (int mi = 0; mi < 4; mi++) kacc[s][mi] = (f32x4){0.f,0.f,0.f,0.f};
#pragma unroll
        for (int kb = 0; kb < 8; kb++) {
            bf16x8 bh0 = wsv[U_KW + ((w    )*8+kb)*64 + lane];
            bf16x8 bh1 = wsv[U_KW + ((w + 8)*8+kb)*64 + lane];
#pragma unroll
            for (int mi = 0; mi < 4; mi++) {
                bf16x8 ah = HFu[(mi*8+kb)*64 + slane];
                kacc[0][mi] = MFMA(ah, bh0, kacc[0][mi]);
                kacc[1][mi] = MFMA(ah, bh1, kacc[1][mi]);
            }
        }
        __syncthreads();   // all enc reads complete before overwrite
#pragma unroll
        for (int s = 0; s < 2; s++) {
            int n = (w + s*8)*16 + lcol;
            int hi = (n>>3)&3, kb2 = n>>5, j2 = n&7;
            float bk = k_b[n];
#pragma unroll
            for (int mi = 0; mi < 4; mi++)       // nt2 = m>>4 = mi
#pragma unroll
                for (int rp = 0; rp < 2; rp++) {
                    unsigned r = pk2(kacc[s][mi][2*rp] + bk, kacc[s][mi][2*rp+1] + bk);
                    int m0 = quad*4 + 2*rp;
                    int gbase = (mi*8 + kb2)*64 + hi*16;
                    sm[SH_H + (gbase + ((m0  )^hi))*8 + j2] = (short)r;
                    sm[SH_H + (gbase + ((m0+1)^hi))*8 + j2] = (short)(r >> 16);
                }
        }
    }
    __syncthreads();

    // ---------- S = Q @ K^T (M=64 rank, N=64 seq, K=256): 16 tiles, 2/wave ----------
#pragma unroll
    for (int it = 0; it < 2; it++) {
        int t = w*2 + it;
        int mi = t >> 2, nt = t & 3;
        f32x4 sacc = (f32x4){0.f,0.f,0.f,0.f};
#pragma unroll
        for (int kb = 0; kb < 8; kb++) {
            bf16x8 bh = HFu[(nt*8+kb)*64 + slane];
            bf16x8 ah = wsv[U_Q + (mi*8+kb)*64 + lane];
            sacc = MFMA(ah, bh, sacc);
        }
#pragma unroll
        for (int reg = 0; reg < 4; reg++) {
            int tt = mi*16 + quad*4 + reg;
            int n = nt*16 + lcol;
            SB[tt*64 + (n ^ ((tt&7)<<2))] = sacc[reg];
        }
    }
    __syncthreads();

    // ---------- greedy pointer decode (wave 0, lane n) ----------
    if (tid < 64) {
        int ln = tid;
        bool alive = true;
        float* outb = out + (size_t)b * (64*64);
        for (int t = 0; t < 64; t++) {
            float v  = SB[t*64 + (ln ^ ((t&7)<<2))];
            float lv = alive ? v : NEG_FILL;
            outb[t*64 + ln] = lv;
            float bv = lv;
#pragma unroll
            for (int off = 32; off >= 1; off >>= 1)
                bv = fmaxf(bv, __shfl_xor(bv, off, 64));
            unsigned long long mk = __ballot(lv == bv);
            int bi = __ffsll(mk) - 1;     // lowest index among max ties = argmax
            if (bi == ln) alive = false;
        }
    }
}

extern "C" void kernel_launch(void* const* d_in, const int* in_sizes, int n_in,
                              void* d_out, int out_size, void* d_ws, size_t ws_size,
                              hipStream_t stream) {
    (void)in_sizes; (void)n_in; (void)out_size; (void)ws_size;  // needs ws_size >= 1,802,240 B
    const float* x          = (const float*)d_in[0];
    const float* ve_w1      = (const float*)d_in[1];
    const float* ve_b1      = (const float*)d_in[2];
    const float* ve_w2      = (const float*)d_in[3];
    const float* ve_b2      = (const float*)d_in[4];
    const float* pos_emb    = (const float*)d_in[5];
    const float* attn_in_w  = (const float*)d_in[6];
    const float* attn_in_b  = (const float*)d_in[7];
    const float* attn_out_w = (const float*)d_in[8];
    const float* attn_out_b = (const float*)d_in[9];
    const float* ffn_w1     = (const float*)d_in[10];
    const float* ffn_b1     = (const float*)d_in[11];
    const float* ffn_w2     = (const float*)d_in[12];
    const float* ffn_b2     = (const float*)d_in[13];
    const float* ln1_g      = (const float*)d_in[14];
    const float* ln1_b      = (const float*)d_in[15];
    const float* ln2_g      = (const float*)d_in[16];
    const float* ln2_b      = (const float*)d_in[17];
    const float* rank_emb   = (const float*)d_in[18];
    const float* q_w        = (const float*)d_in[19];
    const float* q_b        = (const float*)d_in[20];
    const float* k_w        = (const float*)d_in[21];
    const float* k_b        = (const float*)d_in[22];
    float* outp = (float*)d_out;
    short* wsp  = (short*)d_ws;

    (void)hipFuncSetAttribute((const void*)fused_kernel,
                              hipFuncAttributeMaxDynamicSharedMemorySize,
                              (int)LDS_BYTES);

    hipLaunchKernelGGL(prep_q, dim3(64), dim3(256), 0, stream, rank_emb, q_w, q_b, wsp);
    hipLaunchKernelGGL(prep_w, dim3(432), dim3(256), 0, stream,
                       ve_w2, attn_in_w, attn_out_w, ffn_w1, ffn_w2, k_w, wsp);
    hipLaunchKernelGGL(fused_kernel, dim3(4096), dim3(512), LDS_BYTES, stream,
                       x, ve_w1, ve_b1, ve_b2, pos_emb,
                       attn_in_b, attn_out_b,
                       ffn_b1, ffn_b2,
                       ln1_g, ln1_b, ln2_g, ln2_b,
                       k_b, (const short*)wsp, outp);
}